// Round 5
// baseline (359.194 us; speedup 1.0000x reference)
//
#include <hip/hip_runtime.h>
#include <cstdint>
#include <cstddef>

typedef unsigned short u16;
typedef __attribute__((ext_vector_type(8))) __bf16 bf16x8;
typedef __attribute__((ext_vector_type(4))) float f32x4;

__device__ __forceinline__ u16 f2bf(float f) {
  unsigned u = __float_as_uint(f);
  u += 0x7FFFu + ((u >> 16) & 1u);   // round-to-nearest-even
  return (u16)(u >> 16);
}

__device__ __forceinline__ float bf2f(u16 h) {
  return __uint_as_float(((unsigned)h) << 16);
}

__device__ __forceinline__ void async16(u16* lds, const u16* g) {
  __builtin_amdgcn_global_load_lds(
      (const __attribute__((address_space(1))) unsigned int*)g,
      (__attribute__((address_space(3))) unsigned int*)lds, 16, 0, 0);
}

// ---------------- Fused TT weight expansion: one kernel per layer ----------------
// Computes Wt[out*Kin+in] (bf16, B^T layout) from the 4 TT cores entirely in LDS.
// Phase1: B12 (9216 f32) in LDS.  Phase2: this block's B123 chunk (4608 f32).
// Phase3: W elements, 16B vector stores.
template<int I1,int I2,int I3,int I4,int O1,int O2,int O3,int O4,int OUTS>
__global__ __launch_bounds__(256)
void tt_fused(const float* __restrict__ gA, const float* __restrict__ gB,
              const float* __restrict__ gC, const float* __restrict__ gD,
              u16* __restrict__ Wt) {
  constexpr int R1 = 12, R2 = 24, R3 = 12;
  constexpr int O12 = O1 * O2;
  constexpr int fiCnt = I1 * I2 * I3;
  constexpr int Kin = fiCnt * I4;
  constexpr int S = OUTS / O4;            // fo123 span per block
  constexpr int NB12 = I1 * I2 * O12 * R2;  // 9216
  constexpr int NB123 = S * R3 * fiCnt;     // 4608
  __shared__ float sB12[NB12];
  __shared__ float sB123[NB123];
  __shared__ float sgD[R3 * I4 * O4];       // 1536
  const int tid = threadIdx.x;

  // phase 1: B12[fi12][fo12][r2] = sum_r1 gA[i1,o1,r1]*gB[r1,i2,o2,r2]
  for (int e = tid; e < NB12; e += 256) {
    int r2 = e % R2; int t = e / R2;
    int fo12 = t % O12; int fi12 = t / O12;
    int i2 = fi12 % I2, i1 = fi12 / I2;
    int o2 = fo12 % O2, o1 = fo12 / O2;
    float s = 0.f;
#pragma unroll
    for (int r1 = 0; r1 < R1; ++r1)
      s += gA[(i1 * O1 + o1) * R1 + r1] * gB[((r1 * I2 + i2) * O2 + o2) * R2 + r2];
    sB12[e] = s;
  }
  for (int e = tid; e < R3 * I4 * O4; e += 256) sgD[e] = gD[e];
  __syncthreads();

  // phase 2: B123[sl][r3][fi123] = sum_r2 B12[fi12][fo12][r2]*gC[r2,i3,o3,r3]
  const int F0 = blockIdx.x * S;
  for (int e = tid; e < NB123; e += 256) {
    int fi123 = e % fiCnt; int t = e / fiCnt;
    int r3 = t % R3; int sl = t / R3;
    int fo123 = F0 + sl;
    int o3 = fo123 % O3, fo12 = fo123 / O3;
    int i3 = fi123 % I3, fi12 = fi123 / I3;
    float s = 0.f;
#pragma unroll
    for (int r2 = 0; r2 < R2; ++r2)
      s += sB12[(fi12 * O12 + fo12) * R2 + r2] * gC[((r2 * I3 + i3) * O3 + o3) * R3 + r3];
    sB123[(sl * R3 + r3) * fiCnt + fi123] = s;
  }
  __syncthreads();

  // phase 3: Wt[out][fi123*I4 + i4] = sum_r3 B123*gD
  constexpr int PAIRS = OUTS * fiCnt;
  for (int p = tid; p < PAIRS; p += 256) {
    int fi123 = p % fiCnt; int ol = p / fiCnt;
    int out = blockIdx.x * OUTS + ol;
    int o4 = ol % O4; int sl = ol / O4;
    float b[R3];
#pragma unroll
    for (int r3 = 0; r3 < R3; ++r3) b[r3] = sB123[(sl * R3 + r3) * fiCnt + fi123];
    u16 vals[I4];
#pragma unroll
    for (int i4 = 0; i4 < I4; ++i4) {
      float s = 0.f;
#pragma unroll
      for (int r3 = 0; r3 < R3; ++r3) s += b[r3] * sgD[(r3 * I4 + i4) * O4 + o4];
      vals[i4] = f2bf(s);
    }
    uint4* dst = (uint4*)(Wt + (size_t)out * Kin + fi123 * I4);
#pragma unroll
    for (int c = 0; c < I4 / 8; ++c) dst[c] = ((const uint4*)vals)[c];
  }
}

__global__ void cvt_f32_bf16(const float4* __restrict__ in, ushort4* __restrict__ out, int n4) {
  int i = blockIdx.x * 256 + threadIdx.x;
  if (i < n4) {
    float4 v = in[i];
    ushort4 o;
    o.x = f2bf(v.x); o.y = f2bf(v.y); o.z = f2bf(v.z); o.w = f2bf(v.w);
    out[i] = o;
  }
}

// out = bias2 + sum of nz bf16 partials
__global__ void reduceN(const ushort4* __restrict__ P, const float4* __restrict__ b4,
                        float4* __restrict__ out4, int n4, int bn4, int zstride4, int nz) {
  int i = blockIdx.x * 256 + threadIdx.x;
  if (i >= n4) return;
  float4 acc = b4[i % bn4];
  for (int s = 0; s < nz; ++s) {
    ushort4 u = P[i + s * zstride4];
    acc.x += bf2f(u.x); acc.y += bf2f(u.y); acc.z += bf2f(u.z); acc.w += bf2f(u.w);
  }
  out4[i] = acc;
}

// ---------------- bf16 MFMA GEMM, C = A(MxK) * Bt(NxK)^T, BK=32 ----------------
// Epilogue: j-innermost so the 4 stores covering each 128B line issue
// back-to-back (fixes 2.4x HBM write amplification seen in R4).
template <bool GELU, int MINW>
__global__ __launch_bounds__(256, MINW)
void gemm_bt(const u16* __restrict__ A, const u16* __restrict__ Bt,
             const float* __restrict__ bias, u16* __restrict__ Out,
             int N, int K, int klen, size_t zstride) {
  __shared__ __align__(16) u16 As[128 * 32];
  __shared__ __align__(16) u16 Bs[128 * 32];
  const int tid = threadIdx.x;
  const int bm = blockIdx.x, bn = blockIdx.y;
  const int wave = tid >> 6, lane = tid & 63;
  const int wm = (wave & 1) * 64, wn = (wave >> 1) * 64;
  const int lr = lane & 15, lq = lane >> 4;

  const int srow = tid >> 2;
  const int scol = (tid & 3) * 8;
  const u16* Ag = A + (size_t)(bm * 128 + srow) * K + scol;
  const u16* Bg = Bt + (size_t)(bn * 128 + srow) * K + scol;
  u16* AsW = As + tid * 8;
  u16* BsW = Bs + tid * 8;

  f32x4 acc[4][4];
#pragma unroll
  for (int i = 0; i < 4; i++)
#pragma unroll
    for (int j = 0; j < 4; j++) acc[i][j] = (f32x4){0.f, 0.f, 0.f, 0.f};

  const int kbeg = blockIdx.z * klen;
  const int kend = kbeg + klen;
  for (int k0 = kbeg; k0 < kend; k0 += 32) {
    async16(AsW,        Ag + k0);
    async16(AsW + 2048, Ag + k0 + (size_t)64 * K);
    async16(BsW,        Bg + k0);
    async16(BsW + 2048, Bg + k0 + (size_t)64 * K);
    __syncthreads();
    bf16x8 af[4], bfr[4];
#pragma unroll
    for (int i = 0; i < 4; i++)
      af[i] = *(const bf16x8*)(As + (wm + i * 16 + lr) * 32 + lq * 8);
#pragma unroll
    for (int j = 0; j < 4; j++)
      bfr[j] = *(const bf16x8*)(Bs + (wn + j * 16 + lr) * 32 + lq * 8);
#pragma unroll
    for (int i = 0; i < 4; i++)
#pragma unroll
      for (int j = 0; j < 4; j++)
        acc[i][j] = __builtin_amdgcn_mfma_f32_16x16x32_bf16(af[i], bfr[j], acc[i][j], 0, 0, 0);
    __syncthreads();
  }

  u16* Op = Out + blockIdx.z * zstride;
  // C/D layout: col = lane&15, row = (lane>>4)*4 + reg  [verified m89/m91]
  const int r0 = bm * 128 + wm + lq * 4;
  const int c0 = bn * 128 + wn + lr;
  float bv[4];
  if (GELU) {
#pragma unroll
    for (int j = 0; j < 4; j++) bv[j] = bias[c0 + j * 16];
  }
#pragma unroll
  for (int i = 0; i < 4; i++) {
#pragma unroll
    for (int r = 0; r < 4; r++) {
      const size_t rowoff = (size_t)(r0 + i * 16 + r) * N;
#pragma unroll
      for (int j = 0; j < 4; j++) {
        float v = acc[i][j][r];
        if (GELU) {
          v += bv[j];
          v = 0.5f * v * (1.f + erff(v * 0.70710678118654752f));
        }
        Op[rowoff + c0 + j * 16] = f2bf(v);
      }
    }
  }
}

extern "C" void kernel_launch(void* const* d_in, const int* in_sizes, int n_in,
                              void* d_out, int out_size, void* d_ws, size_t ws_size,
                              hipStream_t stream) {
  const float* x   = (const float*)d_in[0];
  const float* g1a = (const float*)d_in[1];
  const float* g1b = (const float*)d_in[2];
  const float* g1c = (const float*)d_in[3];
  const float* g1d = (const float*)d_in[4];
  const float* b1  = (const float*)d_in[5];
  const float* g2a = (const float*)d_in[6];
  const float* g2b = (const float*)d_in[7];
  const float* g2c = (const float*)d_in[8];
  const float* g2d = (const float*)d_in[9];
  const float* b2  = (const float*)d_in[10];
  float* out = (float*)d_out;

  char* ws = (char*)d_ws;
  u16* xb   = (u16*)(ws + 0);          // 4096x768 bf16   = 6291456 B
  u16* W1t  = (u16*)(ws + 6291456);    // 3072x768 bf16   = 4718592 B
  u16* W2t  = (u16*)(ws + 11010048);   // 768x3072 bf16   = 4718592 B
  u16* h    = (u16*)(ws + 15728640);   // 4096x3072 bf16  = 25165824 B
  u16* Part = (u16*)(ws + 40894464);   // nz x 4096x768 bf16

  // split-K factor for GEMM2, guarded by workspace size
  const size_t partBase = 40894464;
  const int nz = (ws_size >= partBase + 8ull * 6291456) ? 8 : 4;

  // x -> bf16
  cvt_f32_bf16<<<3072, 256, 0, stream>>>((const float4*)x, (ushort4*)xb, 786432);

  // fused TT expansion: layer1 I=(4,4,6,8) O=(4,6,8,16); layer2 I=(4,6,8,16) O=(4,4,6,8)
  tt_fused<4,4,6,8, 4,6,8,16, 64><<<48, 256, 0, stream>>>(g1a, g1b, g1c, g1d, W1t);
  tt_fused<4,6,8,16, 4,4,6,8, 16><<<48, 256, 0, stream>>>(g2a, g2b, g2c, g2d, W2t);

  // GEMM1: h = gelu(x @ W1 + b1)   (4096 x 3072, K=768), 768 blocks, 3/CU
  gemm_bt<true, 3><<<dim3(32, 24, 1), 256, 0, stream>>>(xb, W1t, b1, h, 3072, 768, 768, 0);
  // GEMM2: bf16 partials, K=3072 split nz ways, 6 blocks/CU at nz=8
  gemm_bt<false, 6><<<dim3(32, 6, nz), 256, 0, stream>>>(h, W2t, nullptr, Part,
                                                         768, 3072, 3072 / nz, 3145728);
  // out = b2 + sum(partials)
  reduceN<<<3072, 256, 0, stream>>>((const ushort4*)Part, (const float4*)b2,
                                    (float4*)out, 786432, 192, 786432, nz);
}

// Round 6
// 262.004 us; speedup vs baseline: 1.3709x; 1.3709x over previous
//
#include <hip/hip_runtime.h>
#include <cstdint>
#include <cstddef>

typedef unsigned short u16;
typedef __attribute__((ext_vector_type(8))) __bf16 bf16x8;
typedef __attribute__((ext_vector_type(4))) float f32x4;

__device__ __forceinline__ u16 f2bf(float f) {
  unsigned u = __float_as_uint(f);
  u += 0x7FFFu + ((u >> 16) & 1u);   // round-to-nearest-even
  return (u16)(u >> 16);
}

__device__ __forceinline__ float bf2f(u16 h) {
  return __uint_as_float(((unsigned)h) << 16);
}

__device__ __forceinline__ void async16(u16* lds, const u16* g) {
  __builtin_amdgcn_global_load_lds(
      (const __attribute__((address_space(1))) unsigned int*)g,
      (__attribute__((address_space(3))) unsigned int*)lds, 16, 0, 0);
}

// ---------------- Fused TT weight expansion: one kernel per layer ----------------
template<int I1,int I2,int I3,int I4,int O1,int O2,int O3,int O4,int OUTS>
__global__ __launch_bounds__(256)
void tt_fused(const float* __restrict__ gA, const float* __restrict__ gB,
              const float* __restrict__ gC, const float* __restrict__ gD,
              u16* __restrict__ Wt) {
  constexpr int R1 = 12, R2 = 24, R3 = 12;
  constexpr int O12 = O1 * O2;
  constexpr int fiCnt = I1 * I2 * I3;
  constexpr int Kin = fiCnt * I4;
  constexpr int S = OUTS / O4;
  constexpr int NB12 = I1 * I2 * O12 * R2;   // 9216
  constexpr int NB123 = S * R3 * fiCnt;      // 4608
  __shared__ float sB12[NB12];
  __shared__ float sB123[NB123];
  __shared__ float sgD[R3 * I4 * O4];        // 1536
  const int tid = threadIdx.x;

  for (int e = tid; e < NB12; e += 256) {
    int r2 = e % R2; int t = e / R2;
    int fo12 = t % O12; int fi12 = t / O12;
    int i2 = fi12 % I2, i1 = fi12 / I2;
    int o2 = fo12 % O2, o1 = fo12 / O2;
    float s = 0.f;
#pragma unroll
    for (int r1 = 0; r1 < R1; ++r1)
      s += gA[(i1 * O1 + o1) * R1 + r1] * gB[((r1 * I2 + i2) * O2 + o2) * R2 + r2];
    sB12[e] = s;
  }
  for (int e = tid; e < R3 * I4 * O4; e += 256) sgD[e] = gD[e];
  __syncthreads();

  const int F0 = blockIdx.x * S;
  for (int e = tid; e < NB123; e += 256) {
    int fi123 = e % fiCnt; int t = e / fiCnt;
    int r3 = t % R3; int sl = t / R3;
    int fo123 = F0 + sl;
    int o3 = fo123 % O3, fo12 = fo123 / O3;
    int i3 = fi123 % I3, fi12 = fi123 / I3;
    float s = 0.f;
#pragma unroll
    for (int r2 = 0; r2 < R2; ++r2)
      s += sB12[(fi12 * O12 + fo12) * R2 + r2] * gC[((r2 * I3 + i3) * O3 + o3) * R3 + r3];
    sB123[(sl * R3 + r3) * fiCnt + fi123] = s;
  }
  __syncthreads();

  constexpr int PAIRS = OUTS * fiCnt;
  for (int p = tid; p < PAIRS; p += 256) {
    int fi123 = p % fiCnt; int ol = p / fiCnt;
    int out = blockIdx.x * OUTS + ol;
    int o4 = ol % O4; int sl = ol / O4;
    float b[R3];
#pragma unroll
    for (int r3 = 0; r3 < R3; ++r3) b[r3] = sB123[(sl * R3 + r3) * fiCnt + fi123];
    u16 vals[I4];
#pragma unroll
    for (int i4 = 0; i4 < I4; ++i4) {
      float s = 0.f;
#pragma unroll
      for (int r3 = 0; r3 < R3; ++r3) s += b[r3] * sgD[(r3 * I4 + i4) * O4 + o4];
      vals[i4] = f2bf(s);
    }
    uint4* dst = (uint4*)(Wt + (size_t)out * Kin + fi123 * I4);
#pragma unroll
    for (int c = 0; c < I4 / 8; ++c) dst[c] = ((const uint4*)vals)[c];
  }
}

__global__ void cvt_f32_bf16(const float4* __restrict__ in, ushort4* __restrict__ out, int n4) {
  int i = blockIdx.x * 256 + threadIdx.x;
  if (i < n4) {
    float4 v = in[i];
    ushort4 o;
    o.x = f2bf(v.x); o.y = f2bf(v.y); o.z = f2bf(v.z); o.w = f2bf(v.w);
    out[i] = o;
  }
}

// out = bias2 + sum of nz bf16 partials
__global__ void reduceN(const ushort4* __restrict__ P, const float4* __restrict__ b4,
                        float4* __restrict__ out4, int n4, int bn4, int zstride4, int nz) {
  int i = blockIdx.x * 256 + threadIdx.x;
  if (i >= n4) return;
  float4 acc = b4[i % bn4];
  for (int s = 0; s < nz; ++s) {
    ushort4 u = P[i + s * zstride4];
    acc.x += bf2f(u.x); acc.y += bf2f(u.y); acc.z += bf2f(u.z); acc.w += bf2f(u.w);
  }
  out4[i] = acc;
}

// ---------------- bf16 MFMA GEMM, C = A(MxK) * Bt(NxK)^T, BK=32 ----------------
// launch_bounds(256,3): unified VGPR+AGPR budget is 512/3=170 >= ~120 needed
// (56 VGPR + 64 AGPR). MINW>=5 spills accumulators to scratch (R5: 409MB WRITE).
// Epilogue j-innermost: 4 stores covering each 128B line issue back-to-back.
template <bool GELU>
__global__ __launch_bounds__(256, 3)
void gemm_bt(const u16* __restrict__ A, const u16* __restrict__ Bt,
             const float* __restrict__ bias, u16* __restrict__ Out,
             int N, int K, int klen, size_t zstride) {
  __shared__ __align__(16) u16 As[128 * 32];
  __shared__ __align__(16) u16 Bs[128 * 32];
  const int tid = threadIdx.x;
  const int bm = blockIdx.x, bn = blockIdx.y;
  const int wave = tid >> 6, lane = tid & 63;
  const int wm = (wave & 1) * 64, wn = (wave >> 1) * 64;
  const int lr = lane & 15, lq = lane >> 4;

  const int srow = tid >> 2;
  const int scol = (tid & 3) * 8;
  const u16* Ag = A + (size_t)(bm * 128 + srow) * K + scol;
  const u16* Bg = Bt + (size_t)(bn * 128 + srow) * K + scol;
  u16* AsW = As + tid * 8;
  u16* BsW = Bs + tid * 8;

  f32x4 acc[4][4];
#pragma unroll
  for (int i = 0; i < 4; i++)
#pragma unroll
    for (int j = 0; j < 4; j++) acc[i][j] = (f32x4){0.f, 0.f, 0.f, 0.f};

  const int kbeg = blockIdx.z * klen;
  const int kend = kbeg + klen;
  for (int k0 = kbeg; k0 < kend; k0 += 32) {
    async16(AsW,        Ag + k0);
    async16(AsW + 2048, Ag + k0 + (size_t)64 * K);
    async16(BsW,        Bg + k0);
    async16(BsW + 2048, Bg + k0 + (size_t)64 * K);
    __syncthreads();
    bf16x8 af[4], bfr[4];
#pragma unroll
    for (int i = 0; i < 4; i++)
      af[i] = *(const bf16x8*)(As + (wm + i * 16 + lr) * 32 + lq * 8);
#pragma unroll
    for (int j = 0; j < 4; j++)
      bfr[j] = *(const bf16x8*)(Bs + (wn + j * 16 + lr) * 32 + lq * 8);
#pragma unroll
    for (int i = 0; i < 4; i++)
#pragma unroll
      for (int j = 0; j < 4; j++)
        acc[i][j] = __builtin_amdgcn_mfma_f32_16x16x32_bf16(af[i], bfr[j], acc[i][j], 0, 0, 0);
    __syncthreads();
  }

  u16* Op = Out + blockIdx.z * zstride;
  // C/D layout: col = lane&15, row = (lane>>4)*4 + reg  [verified m89/m91]
  const int r0 = bm * 128 + wm + lq * 4;
  const int c0 = bn * 128 + wn + lr;
  float bv[4];
  if (GELU) {
#pragma unroll
    for (int j = 0; j < 4; j++) bv[j] = bias[c0 + j * 16];
  }
#pragma unroll
  for (int i = 0; i < 4; i++) {
#pragma unroll
    for (int r = 0; r < 4; r++) {
      const size_t rowoff = (size_t)(r0 + i * 16 + r) * N;
#pragma unroll
      for (int j = 0; j < 4; j++) {
        float v = acc[i][j][r];
        if (GELU) {
          v += bv[j];
          v = 0.5f * v * (1.f + erff(v * 0.70710678118654752f));
        }
        Op[rowoff + c0 + j * 16] = f2bf(v);
      }
    }
  }
}

extern "C" void kernel_launch(void* const* d_in, const int* in_sizes, int n_in,
                              void* d_out, int out_size, void* d_ws, size_t ws_size,
                              hipStream_t stream) {
  const float* x   = (const float*)d_in[0];
  const float* g1a = (const float*)d_in[1];
  const float* g1b = (const float*)d_in[2];
  const float* g1c = (const float*)d_in[3];
  const float* g1d = (const float*)d_in[4];
  const float* b1  = (const float*)d_in[5];
  const float* g2a = (const float*)d_in[6];
  const float* g2b = (const float*)d_in[7];
  const float* g2c = (const float*)d_in[8];
  const float* g2d = (const float*)d_in[9];
  const float* b2  = (const float*)d_in[10];
  float* out = (float*)d_out;

  char* ws = (char*)d_ws;
  u16* xb   = (u16*)(ws + 0);          // 4096x768 bf16   = 6291456 B
  u16* W1t  = (u16*)(ws + 6291456);    // 3072x768 bf16   = 4718592 B
  u16* W2t  = (u16*)(ws + 11010048);   // 768x3072 bf16   = 4718592 B
  u16* h    = (u16*)(ws + 15728640);   // 4096x3072 bf16  = 25165824 B
  u16* Part = (u16*)(ws + 40894464);   // 4 x 4096x768 bf16 = 25165824 B

  // x -> bf16
  cvt_f32_bf16<<<3072, 256, 0, stream>>>((const float4*)x, (ushort4*)xb, 786432);

  // fused TT expansion: layer1 I=(4,4,6,8) O=(4,6,8,16); layer2 I=(4,6,8,16) O=(4,4,6,8)
  tt_fused<4,4,6,8, 4,6,8,16, 64><<<48, 256, 0, stream>>>(g1a, g1b, g1c, g1d, W1t);
  tt_fused<4,6,8,16, 4,4,6,8, 16><<<48, 256, 0, stream>>>(g2a, g2b, g2c, g2d, W2t);

  // GEMM1: h = gelu(x @ W1 + b1)   (4096 x 3072, K=768), 768 blocks, 3/CU
  gemm_bt<true><<<dim3(32, 24, 1), 256, 0, stream>>>(xb, W1t, b1, h, 3072, 768, 768, 0);
  // GEMM2: bf16 partials, K=3072 split 4 ways, 768 blocks, 3/CU
  gemm_bt<false><<<dim3(32, 6, 4), 256, 0, stream>>>(h, W2t, nullptr, Part,
                                                     768, 3072, 768, 3145728);
  // out = b2 + sum(partials)
  reduceN<<<3072, 256, 0, stream>>>((const ushort4*)Part, (const float4*)b2,
                                    (float4*)out, 786432, 192, 786432, 4);
}

// Round 7
// 183.229 us; speedup vs baseline: 1.9604x; 1.4299x over previous
//
#include <hip/hip_runtime.h>
#include <cstdint>
#include <cstddef>

typedef unsigned short u16;
typedef __attribute__((ext_vector_type(8))) __bf16 bf16x8;
typedef __attribute__((ext_vector_type(4))) float f32x4;

__device__ __forceinline__ u16 f2bf(float f) {
  unsigned u = __float_as_uint(f);
  u += 0x7FFFu + ((u >> 16) & 1u);   // round-to-nearest-even
  return (u16)(u >> 16);
}

__device__ __forceinline__ float bf2f(u16 h) {
  return __uint_as_float(((unsigned)h) << 16);
}

__device__ __forceinline__ void async16(u16* lds, const u16* g) {
  __builtin_amdgcn_global_load_lds(
      (const __attribute__((address_space(1))) unsigned int*)g,
      (__attribute__((address_space(3))) unsigned int*)lds, 16, 0, 0);
}

// ---------------- TT pre-pass: B12 = g1*g2, C34t = g3*g4, both layers ----------------
// B12 layout:  [fi12][fo12][r2]          (9216 f32 per layer)
// C34t layout: [r2][fo34][fi34]          (147456 f32 per layer; fi34 innermost)
// Flat index over 4 segments; 1224 blocks x 256 -> ~4.8 blocks/CU, latency hidden.
__global__ __launch_bounds__(256)
void tt_pre(const float* __restrict__ gA1, const float* __restrict__ gB1,
            const float* __restrict__ gC1, const float* __restrict__ gD1,
            const float* __restrict__ gA2, const float* __restrict__ gB2,
            const float* __restrict__ gC2, const float* __restrict__ gD2,
            float* __restrict__ B12_1, float* __restrict__ B12_2,
            float* __restrict__ C1, float* __restrict__ C2) {
  int idx = blockIdx.x * 256 + threadIdx.x;
  if (idx < 9216) {
    // layer1 B12: I1=4 I2=4 O1=4 O2=6 (O12=24)
    int e = idx;
    int r2 = e % 24; int t = e / 24;
    int fo12 = t % 24, fi12 = t / 24;
    int i2 = fi12 % 4, i1 = fi12 / 4;
    int o2 = fo12 % 6, o1 = fo12 / 6;
    float s = 0.f;
#pragma unroll
    for (int r1 = 0; r1 < 12; ++r1)
      s += gA1[(i1 * 4 + o1) * 12 + r1] * gB1[((r1 * 4 + i2) * 6 + o2) * 24 + r2];
    B12_1[e] = s;
  } else if (idx < 18432) {
    // layer2 B12: I1=4 I2=6 O1=4 O2=4 (O12=16)
    int e = idx - 9216;
    int r2 = e % 24; int t = e / 24;
    int fo12 = t % 16, fi12 = t / 16;
    int i2 = fi12 % 6, i1 = fi12 / 6;
    int o2 = fo12 % 4, o1 = fo12 / 4;
    float s = 0.f;
#pragma unroll
    for (int r1 = 0; r1 < 12; ++r1)
      s += gA2[(i1 * 4 + o1) * 12 + r1] * gB2[((r1 * 6 + i2) * 4 + o2) * 24 + r2];
    B12_2[e] = s;
  } else if (idx < 165888) {
    // layer1 C34t: I3=6 I4=8 (I34=48), O3=8 O4=16 (O34=128)
    int e = idx - 18432;
    int fi34 = e % 48; int t = e / 48;
    int fo34 = t % 128;  // r2 = t / 128
    int i3 = fi34 / 8, i4 = fi34 % 8;
    int o3 = fo34 / 16, o4 = fo34 % 16;
    int r2 = t / 128;
    float s = 0.f;
#pragma unroll
    for (int r3 = 0; r3 < 12; ++r3)
      s += gC1[((r2 * 6 + i3) * 8 + o3) * 12 + r3] * gD1[(r3 * 8 + i4) * 16 + o4];
    C1[e] = s;
  } else {
    // layer2 C34t: I3=8 I4=16 (I34=128), O3=6 O4=8 (O34=48)
    int e = idx - 165888;
    int fi34 = e % 128; int t = e / 128;
    int fo34 = t % 48;
    int i3 = fi34 / 16, i4 = fi34 % 16;
    int o3 = fo34 / 8, o4 = fo34 % 8;
    int r2 = t / 48;
    float s = 0.f;
#pragma unroll
    for (int r3 = 0; r3 < 12; ++r3)
      s += gC2[((r2 * 8 + i3) * 6 + o3) * 12 + r3] * gD2[(r3 * 16 + i4) * 8 + o4];
    C2[e] = s;
  }
}

// ---------------- TT expand: Wt[out][in] = sum_r2 B12[fi12,fo12,r2]*C34t[r2,fo34,fi34] ----
// Thread: 8 contiguous `in` x OG fo12 rows. C34t reads 32B/lane, wave-shared.
// sB padded to 25 floats/r2-row (kills stride-96 -> same-bank conflicts).
template <int FI12, int I34, int O12, int O34, int OG>
__global__ __launch_bounds__(256)
void tt_expand(const float* __restrict__ B12, const float* __restrict__ C34t,
               u16* __restrict__ Wt) {
  constexpr int R2 = 24;
  constexpr int Kin = FI12 * I34;
  constexpr int IC = Kin / 8;
  constexpr int I34C = I34 / 8;
  __shared__ float sB[FI12 * OG * 25];
  const int tid = threadIdx.x;
  const int by = blockIdx.y;
  for (int e = tid; e < FI12 * OG * R2; e += 256) {
    int r2 = e % R2; int t = e / R2;
    int f = t % OG; int fi12 = t / OG;
    sB[(fi12 * OG + f) * 25 + r2] = B12[(fi12 * O12 + by * OG + f) * R2 + r2];
  }
  __syncthreads();
  const int t = blockIdx.x * 256 + tid;
  const int fo34 = t / IC;
  const int ic = t % IC;
  const int fi12 = ic / I34C;
  const int fi34 = (ic % I34C) * 8;

  float acc[OG][8];
#pragma unroll
  for (int f = 0; f < OG; ++f)
#pragma unroll
    for (int k = 0; k < 8; ++k) acc[f][k] = 0.f;

  for (int r2 = 0; r2 < R2; ++r2) {
    const float4* cp = (const float4*)(C34t + ((size_t)(r2 * O34 + fo34) * I34 + fi34));
    float4 c0 = cp[0], c1 = cp[1];
    float c[8] = {c0.x, c0.y, c0.z, c0.w, c1.x, c1.y, c1.z, c1.w};
#pragma unroll
    for (int f = 0; f < OG; ++f) {
      float b = sB[(fi12 * OG + f) * 25 + r2];
#pragma unroll
      for (int k = 0; k < 8; ++k) acc[f][k] += b * c[k];
    }
  }
#pragma unroll
  for (int f = 0; f < OG; ++f) {
    int out = (by * OG + f) * O34 + fo34;
    u16 v[8];
#pragma unroll
    for (int k = 0; k < 8; ++k) v[k] = f2bf(acc[f][k]);
    *(uint4*)(Wt + (size_t)out * Kin + fi12 * I34 + fi34) = *(const uint4*)v;
  }
}

__global__ void cvt_f32_bf16(const float4* __restrict__ in, ushort4* __restrict__ out, int n4) {
  int i = blockIdx.x * 256 + threadIdx.x;
  if (i < n4) {
    float4 v = in[i];
    ushort4 o;
    o.x = f2bf(v.x); o.y = f2bf(v.y); o.z = f2bf(v.z); o.w = f2bf(v.w);
    out[i] = o;
  }
}

// out = bias2 + sum of nz bf16 partials
__global__ void reduceN(const ushort4* __restrict__ P, const float4* __restrict__ b4,
                        float4* __restrict__ out4, int n4, int bn4, int zstride4, int nz) {
  int i = blockIdx.x * 256 + threadIdx.x;
  if (i >= n4) return;
  float4 acc = b4[i % bn4];
  for (int s = 0; s < nz; ++s) {
    ushort4 u = P[i + s * zstride4];
    acc.x += bf2f(u.x); acc.y += bf2f(u.y); acc.z += bf2f(u.z); acc.w += bf2f(u.w);
  }
  out4[i] = acc;
}

// ---------------- bf16 MFMA GEMM, C = A(MxK) * Bt(NxK)^T, BK=32 ----------------
// launch_bounds(256,3): unified VGPR+AGPR budget 512/3=170 >= ~120 needed.
// MINW>=5 spills accumulators to scratch (R5: 409MB WRITE). Epilogue j-innermost.
template <bool GELU>
__global__ __launch_bounds__(256, 3)
void gemm_bt(const u16* __restrict__ A, const u16* __restrict__ Bt,
             const float* __restrict__ bias, u16* __restrict__ Out,
             int N, int K, int klen, size_t zstride) {
  __shared__ __align__(16) u16 As[128 * 32];
  __shared__ __align__(16) u16 Bs[128 * 32];
  const int tid = threadIdx.x;
  const int bm = blockIdx.x, bn = blockIdx.y;
  const int wave = tid >> 6, lane = tid & 63;
  const int wm = (wave & 1) * 64, wn = (wave >> 1) * 64;
  const int lr = lane & 15, lq = lane >> 4;

  const int srow = tid >> 2;
  const int scol = (tid & 3) * 8;
  const u16* Ag = A + (size_t)(bm * 128 + srow) * K + scol;
  const u16* Bg = Bt + (size_t)(bn * 128 + srow) * K + scol;
  u16* AsW = As + tid * 8;
  u16* BsW = Bs + tid * 8;

  f32x4 acc[4][4];
#pragma unroll
  for (int i = 0; i < 4; i++)
#pragma unroll
    for (int j = 0; j < 4; j++) acc[i][j] = (f32x4){0.f, 0.f, 0.f, 0.f};

  const int kbeg = blockIdx.z * klen;
  const int kend = kbeg + klen;
  for (int k0 = kbeg; k0 < kend; k0 += 32) {
    async16(AsW,        Ag + k0);
    async16(AsW + 2048, Ag + k0 + (size_t)64 * K);
    async16(BsW,        Bg + k0);
    async16(BsW + 2048, Bg + k0 + (size_t)64 * K);
    __syncthreads();
    bf16x8 af[4], bfr[4];
#pragma unroll
    for (int i = 0; i < 4; i++)
      af[i] = *(const bf16x8*)(As + (wm + i * 16 + lr) * 32 + lq * 8);
#pragma unroll
    for (int j = 0; j < 4; j++)
      bfr[j] = *(const bf16x8*)(Bs + (wn + j * 16 + lr) * 32 + lq * 8);
#pragma unroll
    for (int i = 0; i < 4; i++)
#pragma unroll
      for (int j = 0; j < 4; j++)
        acc[i][j] = __builtin_amdgcn_mfma_f32_16x16x32_bf16(af[i], bfr[j], acc[i][j], 0, 0, 0);
    __syncthreads();
  }

  u16* Op = Out + blockIdx.z * zstride;
  // C/D layout: col = lane&15, row = (lane>>4)*4 + reg  [verified m89/m91]
  const int r0 = bm * 128 + wm + lq * 4;
  const int c0 = bn * 128 + wn + lr;
  float bv[4];
  if (GELU) {
#pragma unroll
    for (int j = 0; j < 4; j++) bv[j] = bias[c0 + j * 16];
  }
#pragma unroll
  for (int i = 0; i < 4; i++) {
#pragma unroll
    for (int r = 0; r < 4; r++) {
      const size_t rowoff = (size_t)(r0 + i * 16 + r) * N;
#pragma unroll
      for (int j = 0; j < 4; j++) {
        float v = acc[i][j][r];
        if (GELU) {
          v += bv[j];
          v = 0.5f * v * (1.f + erff(v * 0.70710678118654752f));
        }
        Op[rowoff + c0 + j * 16] = f2bf(v);
      }
    }
  }
}

extern "C" void kernel_launch(void* const* d_in, const int* in_sizes, int n_in,
                              void* d_out, int out_size, void* d_ws, size_t ws_size,
                              hipStream_t stream) {
  const float* x   = (const float*)d_in[0];
  const float* g1a = (const float*)d_in[1];
  const float* g1b = (const float*)d_in[2];
  const float* g1c = (const float*)d_in[3];
  const float* g1d = (const float*)d_in[4];
  const float* b1  = (const float*)d_in[5];
  const float* g2a = (const float*)d_in[6];
  const float* g2b = (const float*)d_in[7];
  const float* g2c = (const float*)d_in[8];
  const float* g2d = (const float*)d_in[9];
  const float* b2  = (const float*)d_in[10];
  float* out = (float*)d_out;

  char* ws = (char*)d_ws;
  u16* xb   = (u16*)(ws + 0);          // 4096x768 bf16   = 6291456 B
  u16* W1t  = (u16*)(ws + 6291456);    // 3072x768 bf16   = 4718592 B
  u16* W2t  = (u16*)(ws + 11010048);   // 768x3072 bf16   = 4718592 B
  u16* h    = (u16*)(ws + 15728640);   // 4096x3072 bf16  = 25165824 B
  u16* Part = (u16*)(ws + 40894464);   // 4 x 4096x768 bf16 = 25165824 B
  // TT scratch ALIASES Part (dead before gemm2 writes Part; stream-ordered)
  float* B12_1 = (float*)(ws + 40894464);            // 9216 f32
  float* B12_2 = (float*)(ws + 40894464 + 36864);    // 9216 f32
  float* C1    = (float*)(ws + 40894464 + 73728);    // 147456 f32
  float* C2    = (float*)(ws + 40894464 + 663552);   // 147456 f32

  // x -> bf16
  cvt_f32_bf16<<<3072, 256, 0, stream>>>((const float4*)x, (ushort4*)xb, 786432);

  // TT pre-pass: B12 + C34t for both layers (independent products)
  tt_pre<<<1224, 256, 0, stream>>>(g1a, g1b, g1c, g1d, g2a, g2b, g2c, g2d,
                                   B12_1, B12_2, C1, C2);

  // expand: layer1 FI12=16 I34=48 O12=24 O34=128; layer2 FI12=24 I34=128 O12=16 O34=48
  tt_expand<16, 48, 24, 128, 4><<<dim3(48, 6), 256, 0, stream>>>(B12_1, C1, W1t);
  tt_expand<24, 128, 16, 48, 4><<<dim3(72, 4), 256, 0, stream>>>(B12_2, C2, W2t);

  // GEMM1: h = gelu(x @ W1 + b1)   (4096 x 3072, K=768), 768 blocks, 3/CU
  gemm_bt<true><<<dim3(32, 24, 1), 256, 0, stream>>>(xb, W1t, b1, h, 3072, 768, 768, 0);
  // GEMM2: bf16 partials, K=3072 split 4 ways, 768 blocks, 3/CU
  gemm_bt<false><<<dim3(32, 6, 4), 256, 0, stream>>>(h, W2t, nullptr, Part,
                                                     768, 3072, 768, 3145728);
  // out = b2 + sum(partials)
  reduceN<<<3072, 256, 0, stream>>>((const ushort4*)Part, (const float4*)b2,
                                    (float4*)out, 786432, 192, 786432, 4);
}

// Round 8
// 183.000 us; speedup vs baseline: 1.9628x; 1.0013x over previous
//
#include <hip/hip_runtime.h>
#include <cstdint>
#include <cstddef>

typedef unsigned short u16;
typedef __attribute__((ext_vector_type(8))) __bf16 bf16x8;
typedef __attribute__((ext_vector_type(4))) float f32x4;

__device__ __forceinline__ u16 f2bf(float f) {
  unsigned u = __float_as_uint(f);
  u += 0x7FFFu + ((u >> 16) & 1u);   // round-to-nearest-even
  return (u16)(u >> 16);
}

__device__ __forceinline__ float bf2f(u16 h) {
  return __uint_as_float(((unsigned)h) << 16);
}

__device__ __forceinline__ void async16(u16* lds, const u16* g) {
  __builtin_amdgcn_global_load_lds(
      (const __attribute__((address_space(1))) unsigned int*)g,
      (__attribute__((address_space(3))) unsigned int*)lds, 16, 0, 0);
}

// ---------------- TT pre-pass: B12 = g1*g2, C34t = g3*g4, both layers ----------------
__global__ __launch_bounds__(256)
void tt_pre(const float* __restrict__ gA1, const float* __restrict__ gB1,
            const float* __restrict__ gC1, const float* __restrict__ gD1,
            const float* __restrict__ gA2, const float* __restrict__ gB2,
            const float* __restrict__ gC2, const float* __restrict__ gD2,
            float* __restrict__ B12_1, float* __restrict__ B12_2,
            float* __restrict__ C1, float* __restrict__ C2) {
  int idx = blockIdx.x * 256 + threadIdx.x;
  if (idx < 9216) {
    int e = idx;
    int r2 = e % 24; int t = e / 24;
    int fo12 = t % 24, fi12 = t / 24;
    int i2 = fi12 % 4, i1 = fi12 / 4;
    int o2 = fo12 % 6, o1 = fo12 / 6;
    float s = 0.f;
#pragma unroll
    for (int r1 = 0; r1 < 12; ++r1)
      s += gA1[(i1 * 4 + o1) * 12 + r1] * gB1[((r1 * 4 + i2) * 6 + o2) * 24 + r2];
    B12_1[e] = s;
  } else if (idx < 18432) {
    int e = idx - 9216;
    int r2 = e % 24; int t = e / 24;
    int fo12 = t % 16, fi12 = t / 16;
    int i2 = fi12 % 6, i1 = fi12 / 6;
    int o2 = fo12 % 4, o1 = fo12 / 4;
    float s = 0.f;
#pragma unroll
    for (int r1 = 0; r1 < 12; ++r1)
      s += gA2[(i1 * 4 + o1) * 12 + r1] * gB2[((r1 * 6 + i2) * 4 + o2) * 24 + r2];
    B12_2[e] = s;
  } else if (idx < 165888) {
    int e = idx - 18432;
    int fi34 = e % 48; int t = e / 48;
    int fo34 = t % 128;
    int i3 = fi34 / 8, i4 = fi34 % 8;
    int o3 = fo34 / 16, o4 = fo34 % 16;
    int r2 = t / 128;
    float s = 0.f;
#pragma unroll
    for (int r3 = 0; r3 < 12; ++r3)
      s += gC1[((r2 * 6 + i3) * 8 + o3) * 12 + r3] * gD1[(r3 * 8 + i4) * 16 + o4];
    C1[e] = s;
  } else {
    int e = idx - 165888;
    int fi34 = e % 128; int t = e / 128;
    int fo34 = t % 48;
    int i3 = fi34 / 16, i4 = fi34 % 16;
    int o3 = fo34 / 8, o4 = fo34 % 8;
    int r2 = t / 48;
    float s = 0.f;
#pragma unroll
    for (int r3 = 0; r3 < 12; ++r3)
      s += gC2[((r2 * 8 + i3) * 6 + o3) * 12 + r3] * gD2[(r3 * 16 + i4) * 8 + o4];
    C2[e] = s;
  }
}

// ---------------- TT expand: Wt[out][in] = sum_r2 B12[fi12,fo12,r2]*C34t[r2,fo34,fi34] ----
template <int FI12, int I34, int O12, int O34, int OG>
__global__ __launch_bounds__(256)
void tt_expand(const float* __restrict__ B12, const float* __restrict__ C34t,
               u16* __restrict__ Wt) {
  constexpr int R2 = 24;
  constexpr int Kin = FI12 * I34;
  constexpr int IC = Kin / 8;
  constexpr int I34C = I34 / 8;
  __shared__ float sB[FI12 * OG * 25];
  const int tid = threadIdx.x;
  const int by = blockIdx.y;
  for (int e = tid; e < FI12 * OG * R2; e += 256) {
    int r2 = e % R2; int t = e / R2;
    int f = t % OG; int fi12 = t / OG;
    sB[(fi12 * OG + f) * 25 + r2] = B12[(fi12 * O12 + by * OG + f) * R2 + r2];
  }
  __syncthreads();
  const int t = blockIdx.x * 256 + tid;
  const int fo34 = t / IC;
  const int ic = t % IC;
  const int fi12 = ic / I34C;
  const int fi34 = (ic % I34C) * 8;

  float acc[OG][8];
#pragma unroll
  for (int f = 0; f < OG; ++f)
#pragma unroll
    for (int k = 0; k < 8; ++k) acc[f][k] = 0.f;

  for (int r2 = 0; r2 < R2; ++r2) {
    const float4* cp = (const float4*)(C34t + ((size_t)(r2 * O34 + fo34) * I34 + fi34));
    float4 c0 = cp[0], c1 = cp[1];
    float c[8] = {c0.x, c0.y, c0.z, c0.w, c1.x, c1.y, c1.z, c1.w};
#pragma unroll
    for (int f = 0; f < OG; ++f) {
      float b = sB[(fi12 * OG + f) * 25 + r2];
#pragma unroll
      for (int k = 0; k < 8; ++k) acc[f][k] += b * c[k];
    }
  }
#pragma unroll
  for (int f = 0; f < OG; ++f) {
    int out = (by * OG + f) * O34 + fo34;
    u16 v[8];
#pragma unroll
    for (int k = 0; k < 8; ++k) v[k] = f2bf(acc[f][k]);
    *(uint4*)(Wt + (size_t)out * Kin + fi12 * I34 + fi34) = *(const uint4*)v;
  }
}

__global__ void cvt_f32_bf16(const float4* __restrict__ in, ushort4* __restrict__ out, int n4) {
  int i = blockIdx.x * 256 + threadIdx.x;
  if (i < n4) {
    float4 v = in[i];
    ushort4 o;
    o.x = f2bf(v.x); o.y = f2bf(v.y); o.z = f2bf(v.z); o.w = f2bf(v.w);
    out[i] = o;
  }
}

// out = bias2 + sum of nz bf16 partials; 8 elems/thread, 16B partial loads
__global__ void reduceN8(const uint4* __restrict__ P, const float* __restrict__ bias,
                         float4* __restrict__ out4, int n8, int zstride8, int nz) {
  int i = blockIdx.x * 256 + threadIdx.x;
  if (i >= n8) return;
  int b0 = (i % 96) * 8;   // 768 cols / 8
  float a[8];
#pragma unroll
  for (int k = 0; k < 8; ++k) a[k] = bias[b0 + k];
  for (int s = 0; s < nz; ++s) {
    uint4 u = P[i + s * zstride8];
    const u16* up = (const u16*)&u;
#pragma unroll
    for (int k = 0; k < 8; ++k) a[k] += bf2f(up[k]);
  }
  out4[i * 2]     = (float4){a[0], a[1], a[2], a[3]};
  out4[i * 2 + 1] = (float4){a[4], a[5], a[6], a[7]};
}

// ---------------- bf16 MFMA GEMM, C = A(MxK) * Bt(NxK)^T, BK=32 ----------------
// launch_bounds(256,3): unified VGPR+AGPR budget 512/3=170 >= ~120 needed.
// MINW>=5 spills accumulators to scratch (R5: 409MB WRITE).
// Epilogue: j-outer order — R4-measured 48.5us; the j-inner variant (R6/R7)
// halved HBM WRITE but cost +50% kernel time. Data over theory.
template <bool GELU>
__global__ __launch_bounds__(256, 3)
void gemm_bt(const u16* __restrict__ A, const u16* __restrict__ Bt,
             const float* __restrict__ bias, u16* __restrict__ Out,
             int N, int K, int klen, size_t zstride) {
  __shared__ __align__(16) u16 As[128 * 32];
  __shared__ __align__(16) u16 Bs[128 * 32];
  const int tid = threadIdx.x;
  const int bm = blockIdx.x, bn = blockIdx.y;
  const int wave = tid >> 6, lane = tid & 63;
  const int wm = (wave & 1) * 64, wn = (wave >> 1) * 64;
  const int lr = lane & 15, lq = lane >> 4;

  const int srow = tid >> 2;
  const int scol = (tid & 3) * 8;
  const u16* Ag = A + (size_t)(bm * 128 + srow) * K + scol;
  const u16* Bg = Bt + (size_t)(bn * 128 + srow) * K + scol;
  u16* AsW = As + tid * 8;
  u16* BsW = Bs + tid * 8;

  f32x4 acc[4][4];
#pragma unroll
  for (int i = 0; i < 4; i++)
#pragma unroll
    for (int j = 0; j < 4; j++) acc[i][j] = (f32x4){0.f, 0.f, 0.f, 0.f};

  const int kbeg = blockIdx.z * klen;
  const int kend = kbeg + klen;
  for (int k0 = kbeg; k0 < kend; k0 += 32) {
    async16(AsW,        Ag + k0);
    async16(AsW + 2048, Ag + k0 + (size_t)64 * K);
    async16(BsW,        Bg + k0);
    async16(BsW + 2048, Bg + k0 + (size_t)64 * K);
    __syncthreads();
    bf16x8 af[4], bfr[4];
#pragma unroll
    for (int i = 0; i < 4; i++)
      af[i] = *(const bf16x8*)(As + (wm + i * 16 + lr) * 32 + lq * 8);
#pragma unroll
    for (int j = 0; j < 4; j++)
      bfr[j] = *(const bf16x8*)(Bs + (wn + j * 16 + lr) * 32 + lq * 8);
#pragma unroll
    for (int i = 0; i < 4; i++)
#pragma unroll
      for (int j = 0; j < 4; j++)
        acc[i][j] = __builtin_amdgcn_mfma_f32_16x16x32_bf16(af[i], bfr[j], acc[i][j], 0, 0, 0);
    __syncthreads();
  }

  u16* Op = Out + blockIdx.z * zstride;
  // C/D layout: col = lane&15, row = (lane>>4)*4 + reg  [verified m89/m91]
  const int r0 = bm * 128 + wm + lq * 4;
  const int c0 = bn * 128 + wn + lr;
#pragma unroll
  for (int j = 0; j < 4; j++) {
    const int col = c0 + j * 16;
    const float bv = GELU ? bias[col] : 0.f;
#pragma unroll
    for (int i = 0; i < 4; i++) {
      const int row = r0 + i * 16;
#pragma unroll
      for (int r = 0; r < 4; r++) {
        float v = acc[i][j][r];
        if (GELU) {
          v += bv;
          v = 0.5f * v * (1.f + erff(v * 0.70710678118654752f));
        }
        Op[(size_t)(row + r) * N + col] = f2bf(v);
      }
    }
  }
}

extern "C" void kernel_launch(void* const* d_in, const int* in_sizes, int n_in,
                              void* d_out, int out_size, void* d_ws, size_t ws_size,
                              hipStream_t stream) {
  const float* x   = (const float*)d_in[0];
  const float* g1a = (const float*)d_in[1];
  const float* g1b = (const float*)d_in[2];
  const float* g1c = (const float*)d_in[3];
  const float* g1d = (const float*)d_in[4];
  const float* b1  = (const float*)d_in[5];
  const float* g2a = (const float*)d_in[6];
  const float* g2b = (const float*)d_in[7];
  const float* g2c = (const float*)d_in[8];
  const float* g2d = (const float*)d_in[9];
  const float* b2  = (const float*)d_in[10];
  float* out = (float*)d_out;

  char* ws = (char*)d_ws;
  u16* xb   = (u16*)(ws + 0);          // 4096x768 bf16   = 6291456 B
  u16* W1t  = (u16*)(ws + 6291456);    // 3072x768 bf16   = 4718592 B
  u16* W2t  = (u16*)(ws + 11010048);   // 768x3072 bf16   = 4718592 B
  u16* h    = (u16*)(ws + 15728640);   // 4096x3072 bf16  = 25165824 B
  u16* Part = (u16*)(ws + 40894464);   // 4 x 4096x768 bf16 = 25165824 B
  // TT scratch ALIASES Part (dead before gemm2 writes Part; stream-ordered)
  float* B12_1 = (float*)(ws + 40894464);            // 9216 f32
  float* B12_2 = (float*)(ws + 40894464 + 36864);    // 9216 f32
  float* C1    = (float*)(ws + 40894464 + 73728);    // 147456 f32
  float* C2    = (float*)(ws + 40894464 + 663552);   // 147456 f32

  // x -> bf16
  cvt_f32_bf16<<<3072, 256, 0, stream>>>((const float4*)x, (ushort4*)xb, 786432);

  // TT pre-pass: B12 + C34t for both layers
  tt_pre<<<1224, 256, 0, stream>>>(g1a, g1b, g1c, g1d, g2a, g2b, g2c, g2d,
                                   B12_1, B12_2, C1, C2);

  // expand: layer1 FI12=16 I34=48 O12=24 O34=128; layer2 FI12=24 I34=128 O12=16 O34=48
  tt_expand<16, 48, 24, 128, 4><<<dim3(48, 6), 256, 0, stream>>>(B12_1, C1, W1t);
  tt_expand<24, 128, 16, 48, 4><<<dim3(72, 4), 256, 0, stream>>>(B12_2, C2, W2t);

  // GEMM1: h = gelu(x @ W1 + b1)   (4096 x 3072, K=768), 768 blocks, 3/CU
  gemm_bt<true><<<dim3(32, 24, 1), 256, 0, stream>>>(xb, W1t, b1, h, 3072, 768, 768, 0);
  // GEMM2: bf16 partials, K=3072 split 4 ways, 768 blocks, 3/CU
  gemm_bt<false><<<dim3(32, 6, 4), 256, 0, stream>>>(h, W2t, nullptr, Part,
                                                     768, 3072, 768, 3145728);
  // out = b2 + sum(partials)
  reduceN8<<<1536, 256, 0, stream>>>((const uint4*)Part, b2,
                                     (float4*)out, 393216, 393216, 4);
}

// Round 9
// 181.242 us; speedup vs baseline: 1.9818x; 1.0097x over previous
//
#include <hip/hip_runtime.h>
#include <cstdint>
#include <cstddef>

typedef unsigned short u16;
typedef __attribute__((ext_vector_type(8))) __bf16 bf16x8;
typedef __attribute__((ext_vector_type(4))) float f32x4;

__device__ __forceinline__ u16 f2bf(float f) {
  unsigned u = __float_as_uint(f);
  u += 0x7FFFu + ((u >> 16) & 1u);   // round-to-nearest-even
  return (u16)(u >> 16);
}

__device__ __forceinline__ float bf2f(u16 h) {
  return __uint_as_float(((unsigned)h) << 16);
}

__device__ __forceinline__ void async16(u16* lds, const u16* g) {
  __builtin_amdgcn_global_load_lds(
      (const __attribute__((address_space(1))) unsigned int*)g,
      (__attribute__((address_space(3))) unsigned int*)lds, 16, 0, 0);
}

// ---------------- prep: x->bf16 (blocks 0..3071) + TT pre-pass (blocks 3072..4295) ----
// TT pre: B12 = g1*g2 [fi12][fo12][r2]; C34t = g3*g4 [r2][fo34][fi34], both layers.
__global__ __launch_bounds__(256)
void prep(const float4* __restrict__ x4, ushort4* __restrict__ xb4,
          const float* __restrict__ gA1, const float* __restrict__ gB1,
          const float* __restrict__ gC1, const float* __restrict__ gD1,
          const float* __restrict__ gA2, const float* __restrict__ gB2,
          const float* __restrict__ gC2, const float* __restrict__ gD2,
          float* __restrict__ B12_1, float* __restrict__ B12_2,
          float* __restrict__ C1, float* __restrict__ C2) {
  const int b = blockIdx.x;
  const int tid = threadIdx.x;
  if (b < 3072) {
    int i = b * 256 + tid;
    float4 v = x4[i];
    ushort4 o;
    o.x = f2bf(v.x); o.y = f2bf(v.y); o.z = f2bf(v.z); o.w = f2bf(v.w);
    xb4[i] = o;
    return;
  }
  int idx = (b - 3072) * 256 + tid;
  if (idx < 9216) {
    int e = idx;
    int r2 = e % 24; int t = e / 24;
    int fo12 = t % 24, fi12 = t / 24;
    int i2 = fi12 % 4, i1 = fi12 / 4;
    int o2 = fo12 % 6, o1 = fo12 / 6;
    float s = 0.f;
#pragma unroll
    for (int r1 = 0; r1 < 12; ++r1)
      s += gA1[(i1 * 4 + o1) * 12 + r1] * gB1[((r1 * 4 + i2) * 6 + o2) * 24 + r2];
    B12_1[e] = s;
  } else if (idx < 18432) {
    int e = idx - 9216;
    int r2 = e % 24; int t = e / 24;
    int fo12 = t % 16, fi12 = t / 16;
    int i2 = fi12 % 6, i1 = fi12 / 6;
    int o2 = fo12 % 4, o1 = fo12 / 4;
    float s = 0.f;
#pragma unroll
    for (int r1 = 0; r1 < 12; ++r1)
      s += gA2[(i1 * 4 + o1) * 12 + r1] * gB2[((r1 * 6 + i2) * 4 + o2) * 24 + r2];
    B12_2[e] = s;
  } else if (idx < 165888) {
    int e = idx - 18432;
    int fi34 = e % 48; int t = e / 48;
    int fo34 = t % 128;
    int i3 = fi34 / 8, i4 = fi34 % 8;
    int o3 = fo34 / 16, o4 = fo34 % 16;
    int r2 = t / 128;
    float s = 0.f;
#pragma unroll
    for (int r3 = 0; r3 < 12; ++r3)
      s += gC1[((r2 * 6 + i3) * 8 + o3) * 12 + r3] * gD1[(r3 * 8 + i4) * 16 + o4];
    C1[e] = s;
  } else {
    int e = idx - 165888;
    int fi34 = e % 128; int t = e / 128;
    int fo34 = t % 48;
    int i3 = fi34 / 16, i4 = fi34 % 16;
    int o3 = fo34 / 8, o4 = fo34 % 8;
    int r2 = t / 48;
    float s = 0.f;
#pragma unroll
    for (int r3 = 0; r3 < 12; ++r3)
      s += gC2[((r2 * 8 + i3) * 6 + o3) * 12 + r3] * gD2[(r3 * 16 + i4) * 8 + o4];
    C2[e] = s;
  }
}

// ---------------- TT expand: Wt[out][in] = sum_r2 B12[fi12,fo12,r2]*C34t[r2,fo34,fi34] ----
template <int FI12, int I34, int O12, int O34, int OG>
__global__ __launch_bounds__(256)
void tt_expand(const float* __restrict__ B12, const float* __restrict__ C34t,
               u16* __restrict__ Wt) {
  constexpr int R2 = 24;
  constexpr int Kin = FI12 * I34;
  constexpr int IC = Kin / 8;
  constexpr int I34C = I34 / 8;
  __shared__ float sB[FI12 * OG * 25];
  const int tid = threadIdx.x;
  const int by = blockIdx.y;
  for (int e = tid; e < FI12 * OG * R2; e += 256) {
    int r2 = e % R2; int t = e / R2;
    int f = t % OG; int fi12 = t / OG;
    sB[(fi12 * OG + f) * 25 + r2] = B12[(fi12 * O12 + by * OG + f) * R2 + r2];
  }
  __syncthreads();
  const int t = blockIdx.x * 256 + tid;
  const int fo34 = t / IC;
  const int ic = t % IC;
  const int fi12 = ic / I34C;
  const int fi34 = (ic % I34C) * 8;

  float acc[OG][8];
#pragma unroll
  for (int f = 0; f < OG; ++f)
#pragma unroll
    for (int k = 0; k < 8; ++k) acc[f][k] = 0.f;

  for (int r2 = 0; r2 < R2; ++r2) {
    const float4* cp = (const float4*)(C34t + ((size_t)(r2 * O34 + fo34) * I34 + fi34));
    float4 c0 = cp[0], c1 = cp[1];
    float c[8] = {c0.x, c0.y, c0.z, c0.w, c1.x, c1.y, c1.z, c1.w};
#pragma unroll
    for (int f = 0; f < OG; ++f) {
      float bb = sB[(fi12 * OG + f) * 25 + r2];
#pragma unroll
      for (int k = 0; k < 8; ++k) acc[f][k] += bb * c[k];
    }
  }
#pragma unroll
  for (int f = 0; f < OG; ++f) {
    int out = (by * OG + f) * O34 + fo34;
    u16 v[8];
#pragma unroll
    for (int k = 0; k < 8; ++k) v[k] = f2bf(acc[f][k]);
    *(uint4*)(Wt + (size_t)out * Kin + fi12 * I34 + fi34) = *(const uint4*)v;
  }
}

// out = bias2 + sum of nz bf16 partials; 8 elems/thread, 16B partial loads
__global__ void reduceN8(const uint4* __restrict__ P, const float* __restrict__ bias,
                         float4* __restrict__ out4, int n8, int zstride8, int nz) {
  int i = blockIdx.x * 256 + threadIdx.x;
  if (i >= n8) return;
  int b0 = (i % 96) * 8;   // 768 cols / 8
  float a[8];
#pragma unroll
  for (int k = 0; k < 8; ++k) a[k] = bias[b0 + k];
  for (int s = 0; s < nz; ++s) {
    uint4 u = P[i + s * zstride8];
    const u16* up = (const u16*)&u;
#pragma unroll
    for (int k = 0; k < 8; ++k) a[k] += bf2f(up[k]);
  }
  out4[i * 2]     = (float4){a[0], a[1], a[2], a[3]};
  out4[i * 2 + 1] = (float4){a[4], a[5], a[6], a[7]};
}

// ---------------- bf16 MFMA GEMM, C = A(MxK) * Bt(NxK)^T ----------------
// BK=32, DOUBLE-BUFFERED LDS, 1 barrier/iter (unrolled x2 for static buffer idx):
// staging for iter k+1 issues before compute of iter k, so the vmcnt(0) drain
// at the barrier overlaps ~a compute phase instead of exposing full load latency.
// launch_bounds(256,3): 56 VGPR + 64 AGPR = 120 regs -> HW allows 4 waves/SIMD;
// MINW>=5 spills accumulators (R5: 409MB scratch WRITE).
// Epilogue j-innermost: R7-vs-R8 same-chip A/B: j-inner 72-79us vs j-outer 79-89us,
// and WRITE_SIZE 24.5MB vs 61MB. Keep j-inner.
template <bool GELU>
__global__ __launch_bounds__(256, 3)
void gemm_bt(const u16* __restrict__ A, const u16* __restrict__ Bt,
             const float* __restrict__ bias, u16* __restrict__ Out,
             int N, int K, int klen, size_t zstride) {
  __shared__ __align__(16) u16 As[2][128 * 32];
  __shared__ __align__(16) u16 Bs[2][128 * 32];
  const int tid = threadIdx.x;
  const int bm = blockIdx.x, bn = blockIdx.y;
  const int wave = tid >> 6, lane = tid & 63;
  const int wm = (wave & 1) * 64, wn = (wave >> 1) * 64;
  const int lr = lane & 15, lq = lane >> 4;

  const int srow = tid >> 2;
  const int scol = (tid & 3) * 8;
  const u16* Ag = A + (size_t)(bm * 128 + srow) * K + scol;
  const u16* Bg = Bt + (size_t)(bn * 128 + srow) * K + scol;
  u16* AsW = &As[0][0] + tid * 8;
  u16* BsW = &Bs[0][0] + tid * 8;

  f32x4 acc[4][4];
#pragma unroll
  for (int i = 0; i < 4; i++)
#pragma unroll
    for (int j = 0; j < 4; j++) acc[i][j] = (f32x4){0.f, 0.f, 0.f, 0.f};

  const int kbeg = blockIdx.z * klen;
  const int nIter = klen >> 5;   // 24 or 12 (even)

  auto stage = [&](int buf, int k0) {
    async16(AsW + buf * 4096,        Ag + k0);
    async16(AsW + buf * 4096 + 2048, Ag + k0 + (size_t)64 * K);
    async16(BsW + buf * 4096,        Bg + k0);
    async16(BsW + buf * 4096 + 2048, Bg + k0 + (size_t)64 * K);
  };
  auto compute = [&](int buf) {
    bf16x8 af[4], bfr[4];
#pragma unroll
    for (int i = 0; i < 4; i++)
      af[i] = *(const bf16x8*)(&As[buf][0] + (wm + i * 16 + lr) * 32 + lq * 8);
#pragma unroll
    for (int j = 0; j < 4; j++)
      bfr[j] = *(const bf16x8*)(&Bs[buf][0] + (wn + j * 16 + lr) * 32 + lq * 8);
#pragma unroll
    for (int i = 0; i < 4; i++)
#pragma unroll
      for (int j = 0; j < 4; j++)
        acc[i][j] = __builtin_amdgcn_mfma_f32_16x16x32_bf16(af[i], bfr[j], acc[i][j], 0, 0, 0);
  };

  stage(0, kbeg);                      // prologue
  for (int it = 0; it < nIter; it += 2) {
    __syncthreads();                   // buf0 staging complete; buf1 readers done
    if (it + 1 < nIter) stage(1, kbeg + (it + 1) * 32);
    compute(0);
    __syncthreads();                   // buf1 staging complete; buf0 readers done
    if (it + 2 < nIter) stage(0, kbeg + (it + 2) * 32);
    compute(1);
  }

  u16* Op = Out + blockIdx.z * zstride;
  // C/D layout: col = lane&15, row = (lane>>4)*4 + reg  [verified m89/m91]
  const int r0 = bm * 128 + wm + lq * 4;
  const int c0 = bn * 128 + wn + lr;
  float bv[4];
  if (GELU) {
#pragma unroll
    for (int j = 0; j < 4; j++) bv[j] = bias[c0 + j * 16];
  }
#pragma unroll
  for (int i = 0; i < 4; i++) {
#pragma unroll
    for (int r = 0; r < 4; r++) {
      const size_t rowoff = (size_t)(r0 + i * 16 + r) * N;
#pragma unroll
      for (int j = 0; j < 4; j++) {
        float v = acc[i][j][r];
        if (GELU) {
          v += bv[j];
          v = 0.5f * v * (1.f + erff(v * 0.70710678118654752f));
        }
        Op[rowoff + c0 + j * 16] = f2bf(v);
      }
    }
  }
}

extern "C" void kernel_launch(void* const* d_in, const int* in_sizes, int n_in,
                              void* d_out, int out_size, void* d_ws, size_t ws_size,
                              hipStream_t stream) {
  const float* x   = (const float*)d_in[0];
  const float* g1a = (const float*)d_in[1];
  const float* g1b = (const float*)d_in[2];
  const float* g1c = (const float*)d_in[3];
  const float* g1d = (const float*)d_in[4];
  const float* b1  = (const float*)d_in[5];
  const float* g2a = (const float*)d_in[6];
  const float* g2b = (const float*)d_in[7];
  const float* g2c = (const float*)d_in[8];
  const float* g2d = (const float*)d_in[9];
  const float* b2  = (const float*)d_in[10];
  float* out = (float*)d_out;

  char* ws = (char*)d_ws;
  u16* xb   = (u16*)(ws + 0);          // 4096x768 bf16   = 6291456 B
  u16* W1t  = (u16*)(ws + 6291456);    // 3072x768 bf16   = 4718592 B
  u16* W2t  = (u16*)(ws + 11010048);   // 768x3072 bf16   = 4718592 B
  u16* h    = (u16*)(ws + 15728640);   // 4096x3072 bf16  = 25165824 B
  u16* Part = (u16*)(ws + 40894464);   // 4 x 4096x768 bf16 = 25165824 B
  // TT scratch ALIASES Part (dead before gemm2 writes Part; stream-ordered)
  float* B12_1 = (float*)(ws + 40894464);            // 9216 f32
  float* B12_2 = (float*)(ws + 40894464 + 36864);    // 9216 f32
  float* C1    = (float*)(ws + 40894464 + 73728);    // 147456 f32
  float* C2    = (float*)(ws + 40894464 + 663552);   // 147456 f32

  // x->bf16 (blocks 0..3071) + TT pre-pass (blocks 3072..4295)
  prep<<<4296, 256, 0, stream>>>((const float4*)x, (ushort4*)xb,
                                 g1a, g1b, g1c, g1d, g2a, g2b, g2c, g2d,
                                 B12_1, B12_2, C1, C2);

  // expand: layer1 FI12=16 I34=48 O12=24 O34=128; layer2 FI12=24 I34=128 O12=16 O34=48
  tt_expand<16, 48, 24, 128, 4><<<dim3(48, 6), 256, 0, stream>>>(B12_1, C1, W1t);
  tt_expand<24, 128, 16, 48, 4><<<dim3(72, 4), 256, 0, stream>>>(B12_2, C2, W2t);

  // GEMM1: h = gelu(x @ W1 + b1)   (4096 x 3072, K=768), 768 blocks, 3/CU
  gemm_bt<true><<<dim3(32, 24, 1), 256, 0, stream>>>(xb, W1t, b1, h, 3072, 768, 768, 0);
  // GEMM2: bf16 partials, K=3072 split 4 ways, 768 blocks, 3/CU
  gemm_bt<false><<<dim3(32, 6, 4), 256, 0, stream>>>(h, W2t, nullptr, Part,
                                                     768, 3072, 768, 3145728);
  // out = b2 + sum(partials)
  reduceN8<<<1536, 256, 0, stream>>>((const uint4*)Part, b2,
                                     (float4*)out, 393216, 393216, 4);
}

// Round 10
// 176.429 us; speedup vs baseline: 2.0359x; 1.0273x over previous
//
#include <hip/hip_runtime.h>
#include <cstdint>
#include <cstddef>

typedef unsigned short u16;
typedef __attribute__((ext_vector_type(8))) __bf16 bf16x8;
typedef __attribute__((ext_vector_type(4))) float f32x4;

__device__ __forceinline__ u16 f2bf(float f) {
  unsigned u = __float_as_uint(f);
  u += 0x7FFFu + ((u >> 16) & 1u);   // round-to-nearest-even
  return (u16)(u >> 16);
}

__device__ __forceinline__ float bf2f(u16 h) {
  return __uint_as_float(((unsigned)h) << 16);
}

__device__ __forceinline__ void async16(u16* lds, const u16* g) {
  __builtin_amdgcn_global_load_lds(
      (const __attribute__((address_space(1))) unsigned int*)g,
      (__attribute__((address_space(3))) unsigned int*)lds, 16, 0, 0);
}

// ---------------- prep: x->bf16 (blocks 0..3071) + TT pre-pass (blocks 3072..4295) ----
__global__ __launch_bounds__(256)
void prep(const float4* __restrict__ x4, ushort4* __restrict__ xb4,
          const float* __restrict__ gA1, const float* __restrict__ gB1,
          const float* __restrict__ gC1, const float* __restrict__ gD1,
          const float* __restrict__ gA2, const float* __restrict__ gB2,
          const float* __restrict__ gC2, const float* __restrict__ gD2,
          float* __restrict__ B12_1, float* __restrict__ B12_2,
          float* __restrict__ C1, float* __restrict__ C2) {
  const int b = blockIdx.x;
  const int tid = threadIdx.x;
  if (b < 3072) {
    int i = b * 256 + tid;
    float4 v = x4[i];
    ushort4 o;
    o.x = f2bf(v.x); o.y = f2bf(v.y); o.z = f2bf(v.z); o.w = f2bf(v.w);
    xb4[i] = o;
    return;
  }
  int idx = (b - 3072) * 256 + tid;
  if (idx < 9216) {
    int e = idx;
    int r2 = e % 24; int t = e / 24;
    int fo12 = t % 24, fi12 = t / 24;
    int i2 = fi12 % 4, i1 = fi12 / 4;
    int o2 = fo12 % 6, o1 = fo12 / 6;
    float s = 0.f;
#pragma unroll
    for (int r1 = 0; r1 < 12; ++r1)
      s += gA1[(i1 * 4 + o1) * 12 + r1] * gB1[((r1 * 4 + i2) * 6 + o2) * 24 + r2];
    B12_1[e] = s;
  } else if (idx < 18432) {
    int e = idx - 9216;
    int r2 = e % 24; int t = e / 24;
    int fo12 = t % 16, fi12 = t / 16;
    int i2 = fi12 % 6, i1 = fi12 / 6;
    int o2 = fo12 % 4, o1 = fo12 / 4;
    float s = 0.f;
#pragma unroll
    for (int r1 = 0; r1 < 12; ++r1)
      s += gA2[(i1 * 4 + o1) * 12 + r1] * gB2[((r1 * 6 + i2) * 4 + o2) * 24 + r2];
    B12_2[e] = s;
  } else if (idx < 165888) {
    int e = idx - 18432;
    int fi34 = e % 48; int t = e / 48;
    int fo34 = t % 128;
    int i3 = fi34 / 8, i4 = fi34 % 8;
    int o3 = fo34 / 16, o4 = fo34 % 16;
    int r2 = t / 128;
    float s = 0.f;
#pragma unroll
    for (int r3 = 0; r3 < 12; ++r3)
      s += gC1[((r2 * 6 + i3) * 8 + o3) * 12 + r3] * gD1[(r3 * 8 + i4) * 16 + o4];
    C1[e] = s;
  } else {
    int e = idx - 165888;
    int fi34 = e % 128; int t = e / 128;
    int fo34 = t % 48;
    int i3 = fi34 / 16, i4 = fi34 % 16;
    int o3 = fo34 / 8, o4 = fo34 % 8;
    int r2 = t / 48;
    float s = 0.f;
#pragma unroll
    for (int r3 = 0; r3 < 12; ++r3)
      s += gC2[((r2 * 8 + i3) * 6 + o3) * 12 + r3] * gD2[(r3 * 16 + i4) * 8 + o4];
    C2[e] = s;
  }
}

// ---------------- TT expand (device body): Wt[out][in] = sum_r2 B12*C34t ----------------
template <int FI12, int I34, int O12, int O34, int OG>
__device__ __forceinline__
void tt_expand_body(const float* __restrict__ B12, const float* __restrict__ C34t,
                    u16* __restrict__ Wt, int bx, int by, int tid, float* sB) {
  constexpr int R2 = 24;
  constexpr int Kin = FI12 * I34;
  constexpr int IC = Kin / 8;
  constexpr int I34C = I34 / 8;
  for (int e = tid; e < FI12 * OG * R2; e += 256) {
    int r2 = e % R2; int t = e / R2;
    int f = t % OG; int fi12 = t / OG;
    sB[(fi12 * OG + f) * 25 + r2] = B12[(fi12 * O12 + by * OG + f) * R2 + r2];
  }
  __syncthreads();
  const int t = bx * 256 + tid;
  const int fo34 = t / IC;
  const int ic = t % IC;
  const int fi12 = ic / I34C;
  const int fi34 = (ic % I34C) * 8;

  float acc[OG][8];
#pragma unroll
  for (int f = 0; f < OG; ++f)
#pragma unroll
    for (int k = 0; k < 8; ++k) acc[f][k] = 0.f;

  for (int r2 = 0; r2 < R2; ++r2) {
    const float4* cp = (const float4*)(C34t + ((size_t)(r2 * O34 + fo34) * I34 + fi34));
    float4 c0 = cp[0], c1 = cp[1];
    float c[8] = {c0.x, c0.y, c0.z, c0.w, c1.x, c1.y, c1.z, c1.w};
#pragma unroll
    for (int f = 0; f < OG; ++f) {
      float bb = sB[(fi12 * OG + f) * 25 + r2];
#pragma unroll
      for (int k = 0; k < 8; ++k) acc[f][k] += bb * c[k];
    }
  }
#pragma unroll
  for (int f = 0; f < OG; ++f) {
    int out = (by * OG + f) * O34 + fo34;
    u16 v[8];
#pragma unroll
    for (int k = 0; k < 8; ++k) v[k] = f2bf(acc[f][k]);
    *(uint4*)(Wt + (size_t)out * Kin + fi12 * I34 + fi34) = *(const uint4*)v;
  }
}

// Merged: blocks 0..287 -> layer1 (48x6); blocks 288..575 -> layer2 (72x4)
__global__ __launch_bounds__(256)
void tt_expand2(const float* __restrict__ B12_1, const float* __restrict__ C1, u16* __restrict__ W1t,
                const float* __restrict__ B12_2, const float* __restrict__ C2, u16* __restrict__ W2t) {
  __shared__ float sB[24 * 4 * 25];   // max(FI12*OG)=96 rows x 25
  const int b = blockIdx.x;
  const int tid = threadIdx.x;
  if (b < 288) {
    tt_expand_body<16, 48, 24, 128, 4>(B12_1, C1, W1t, b % 48, b / 48, tid, sB);
  } else {
    int bb = b - 288;
    tt_expand_body<24, 128, 16, 48, 4>(B12_2, C2, W2t, bb % 72, bb / 72, tid, sB);
  }
}

// out = bias2 + sum of nz bf16 partials; 8 elems/thread, 16B partial loads
__global__ void reduceN8(const uint4* __restrict__ P, const float* __restrict__ bias,
                         float4* __restrict__ out4, int n8, int zstride8, int nz) {
  int i = blockIdx.x * 256 + threadIdx.x;
  if (i >= n8) return;
  int b0 = (i % 96) * 8;   // 768 cols / 8
  float a[8];
#pragma unroll
  for (int k = 0; k < 8; ++k) a[k] = bias[b0 + k];
  for (int s = 0; s < nz; ++s) {
    uint4 u = P[i + s * zstride8];
    const u16* up = (const u16*)&u;
#pragma unroll
    for (int k = 0; k < 8; ++k) a[k] += bf2f(up[k]);
  }
  out4[i * 2]     = (float4){a[0], a[1], a[2], a[3]};
  out4[i * 2 + 1] = (float4){a[4], a[5], a[6], a[7]};
}

// ---------------- bf16 MFMA GEMM, C = A(MxK) * Bt(NxK)^T ----------------
// BK=32, double-buffered LDS, 1 barrier/iter (R9: 79-89 -> 40us, MfmaUtil 2x).
// MINW: 56 VGPR + 64 AGPR = 120 regs. MINW=4 caps at 128 (safe for the no-GELU
// instantiation, measured 56 VGPR); MINW>=5 spills (R5: 409MB scratch WRITE).
// Epilogue j-innermost (R7-vs-R8 same-chip A/B: faster + 2.4x less HBM write).
template <bool GELU, int MINW>
__global__ __launch_bounds__(256, MINW)
void gemm_bt(const u16* __restrict__ A, const u16* __restrict__ Bt,
             const float* __restrict__ bias, u16* __restrict__ Out,
             int N, int K, int klen, size_t zstride) {
  __shared__ __align__(16) u16 As[2][128 * 32];
  __shared__ __align__(16) u16 Bs[2][128 * 32];
  const int tid = threadIdx.x;
  const int bm = blockIdx.x, bn = blockIdx.y;
  const int wave = tid >> 6, lane = tid & 63;
  const int wm = (wave & 1) * 64, wn = (wave >> 1) * 64;
  const int lr = lane & 15, lq = lane >> 4;

  const int srow = tid >> 2;
  const int scol = (tid & 3) * 8;
  const u16* Ag = A + (size_t)(bm * 128 + srow) * K + scol;
  const u16* Bg = Bt + (size_t)(bn * 128 + srow) * K + scol;
  u16* AsW = &As[0][0] + tid * 8;
  u16* BsW = &Bs[0][0] + tid * 8;

  f32x4 acc[4][4];
#pragma unroll
  for (int i = 0; i < 4; i++)
#pragma unroll
    for (int j = 0; j < 4; j++) acc[i][j] = (f32x4){0.f, 0.f, 0.f, 0.f};

  const int kbeg = blockIdx.z * klen;
  const int nIter = klen >> 5;   // even

  auto stage = [&](int buf, int k0) {
    async16(AsW + buf * 4096,        Ag + k0);
    async16(AsW + buf * 4096 + 2048, Ag + k0 + (size_t)64 * K);
    async16(BsW + buf * 4096,        Bg + k0);
    async16(BsW + buf * 4096 + 2048, Bg + k0 + (size_t)64 * K);
  };
  auto compute = [&](int buf) {
    bf16x8 af[4], bfr[4];
#pragma unroll
    for (int i = 0; i < 4; i++)
      af[i] = *(const bf16x8*)(&As[buf][0] + (wm + i * 16 + lr) * 32 + lq * 8);
#pragma unroll
    for (int j = 0; j < 4; j++)
      bfr[j] = *(const bf16x8*)(&Bs[buf][0] + (wn + j * 16 + lr) * 32 + lq * 8);
#pragma unroll
    for (int i = 0; i < 4; i++)
#pragma unroll
      for (int j = 0; j < 4; j++)
        acc[i][j] = __builtin_amdgcn_mfma_f32_16x16x32_bf16(af[i], bfr[j], acc[i][j], 0, 0, 0);
  };

  stage(0, kbeg);                      // prologue
  for (int it = 0; it < nIter; it += 2) {
    __syncthreads();
    if (it + 1 < nIter) stage(1, kbeg + (it + 1) * 32);
    compute(0);
    __syncthreads();
    if (it + 2 < nIter) stage(0, kbeg + (it + 2) * 32);
    compute(1);
  }

  u16* Op = Out + blockIdx.z * zstride;
  // C/D layout: col = lane&15, row = (lane>>4)*4 + reg  [verified m89/m91]
  const int r0 = bm * 128 + wm + lq * 4;
  const int c0 = bn * 128 + wn + lr;
  float bv[4];
  if (GELU) {
#pragma unroll
    for (int j = 0; j < 4; j++) bv[j] = bias[c0 + j * 16];
  }
#pragma unroll
  for (int i = 0; i < 4; i++) {
#pragma unroll
    for (int r = 0; r < 4; r++) {
      const size_t rowoff = (size_t)(r0 + i * 16 + r) * N;
#pragma unroll
      for (int j = 0; j < 4; j++) {
        float v = acc[i][j][r];
        if (GELU) {
          v += bv[j];
          v = 0.5f * v * (1.f + erff(v * 0.70710678118654752f));
        }
        Op[rowoff + c0 + j * 16] = f2bf(v);
      }
    }
  }
}

extern "C" void kernel_launch(void* const* d_in, const int* in_sizes, int n_in,
                              void* d_out, int out_size, void* d_ws, size_t ws_size,
                              hipStream_t stream) {
  const float* x   = (const float*)d_in[0];
  const float* g1a = (const float*)d_in[1];
  const float* g1b = (const float*)d_in[2];
  const float* g1c = (const float*)d_in[3];
  const float* g1d = (const float*)d_in[4];
  const float* b1  = (const float*)d_in[5];
  const float* g2a = (const float*)d_in[6];
  const float* g2b = (const float*)d_in[7];
  const float* g2c = (const float*)d_in[8];
  const float* g2d = (const float*)d_in[9];
  const float* b2  = (const float*)d_in[10];
  float* out = (float*)d_out;

  char* ws = (char*)d_ws;
  u16* xb   = (u16*)(ws + 0);          // 4096x768 bf16   = 6291456 B
  u16* W1t  = (u16*)(ws + 6291456);    // 3072x768 bf16   = 4718592 B
  u16* W2t  = (u16*)(ws + 11010048);   // 768x3072 bf16   = 4718592 B
  u16* h    = (u16*)(ws + 15728640);   // 4096x3072 bf16  = 25165824 B
  u16* Part = (u16*)(ws + 40894464);   // nz x 4096x768 bf16
  // TT scratch ALIASES Part (dead before gemm2 writes Part; stream-ordered)
  float* B12_1 = (float*)(ws + 40894464);            // 9216 f32
  float* B12_2 = (float*)(ws + 40894464 + 36864);    // 9216 f32
  float* C1    = (float*)(ws + 40894464 + 73728);    // 147456 f32
  float* C2    = (float*)(ws + 40894464 + 663552);   // 147456 f32

  // split-K factor for GEMM2, guarded by workspace size (needs nz partial buffers)
  const int nz = (ws_size >= 40894464ull + 8ull * 6291456ull) ? 8 : 4;

  // x->bf16 (blocks 0..3071) + TT pre-pass (blocks 3072..4295)
  prep<<<4296, 256, 0, stream>>>((const float4*)x, (ushort4*)xb,
                                 g1a, g1b, g1c, g1d, g2a, g2b, g2c, g2d,
                                 B12_1, B12_2, C1, C2);

  // merged expand: layer1 (blocks 0..287) + layer2 (blocks 288..575)
  tt_expand2<<<576, 256, 0, stream>>>(B12_1, C1, W1t, B12_2, C2, W2t);

  // GEMM1: h = gelu(x @ W1 + b1)   (4096 x 3072, K=768), 768 blocks = 3/CU
  gemm_bt<true, 3><<<dim3(32, 24, 1), 256, 0, stream>>>(xb, W1t, b1, h, 3072, 768, 768, 0);
  // GEMM2: bf16 partials, K=3072 split nz ways; nz=8 -> 1536 blocks = 6/CU, 12 iters
  gemm_bt<false, 4><<<dim3(32, 6, nz), 256, 0, stream>>>(h, W2t, nullptr, Part,
                                                         768, 3072, 3072 / nz, 3145728);
  // out = b2 + sum(partials)
  reduceN8<<<1536, 256, 0, stream>>>((const uint4*)Part, b2,
                                     (float4*)out, 393216, 393216, nz);
}